// Round 3
// baseline (7327.306 us; speedup 1.0000x reference)
//
#include <hip/hip_runtime.h>

// ---------------- problem constants ----------------
constexpr int N_   = 512;
constexpr int PIX  = 1024;    // 32*32
constexpr int L_   = 1024;
constexpr int F_   = 32768;   // 32*32*32
constexpr int H_   = 512;
constexpr float IC_ = 1.0f / (float)(512 * 1024);   // 1/(N*PIX), BN count

__device__ __forceinline__ float lrelu(float t) { return t >= 0.f ? t : 0.01f * t; }

// ================= conv 3x3 SAME, NCHW — fused input-BN + stats epilogue ======
// Block: 256 threads, one n, COPB output channels. Thread owns a 4-px vertical
// strip (rows y0..y0+3, col x). Planes staged CT=4 at a time into LDS with
// ZERO-PADDED halo rows (-1 and 32): only column halo needs cndmask (masks
// hoisted). LDS ~17.5 KB -> 4-5 blocks/CU (round-1 version was 33 KB -> 2).
// If BN_IN: BN+lrelu applied (from raw sums in stats_in) while staging.
// Epilogue: writes raw conv+bias, block-reduces per-channel sum/sumsq into
// stats_out[{c, Cout+c}].
template<int CIN, int COPB, bool BN_IN>
__global__ __launch_bounds__(256) void conv3x3(
    const float* __restrict__ in, const float* __restrict__ w,
    const float* __restrict__ bias, float* __restrict__ out,
    const float* __restrict__ stats_in, float* __restrict__ stats_out,
    int Cout)
{
    constexpr int CT  = (CIN < 4) ? CIN : 4;
    constexpr int PST = 34 * 32;               // padded plane: rows -1..32
    __shared__ float tile[CT * PST + 8];       // +4 guard floats each end
    __shared__ float red[2 * COPB];
    const int groups = Cout / COPB;
    const int n   = blockIdx.x / groups;
    const int co0 = (blockIdx.x % groups) * COPB;
    const int tid = threadIdx.x;
    const int x   = tid & 31;
    const int y0  = (tid >> 5) * 4;
    const bool mL = (x > 0), mR = (x < 31);

    // zero halo rows (row -1 at plane offset 0, row 32 at offset 1056) + guards
    if (tid < CT * 64) {
        const int p = tid >> 6, j = tid & 63;
        tile[4 + p * PST + ((j < 32) ? j : (1056 + (j & 31)))] = 0.f;
    }
    if (tid == 254) { tile[0] = tile[1] = tile[2] = tile[3] = 0.f; }
    if (tid == 255) {
        tile[4 + CT * PST] = tile[5 + CT * PST] = 0.f;
        tile[6 + CT * PST] = tile[7 + CT * PST] = 0.f;
    }

    float acc[COPB][4];
#pragma unroll
    for (int c = 0; c < COPB; ++c)
#pragma unroll
        for (int j = 0; j < 4; ++j) acc[c][j] = 0.f;

    const float* inbase = in + (size_t)n * CIN * PIX;

#pragma unroll 1
    for (int s0 = 0; s0 < CIN; s0 += CT) {
        __syncthreads();
#pragma unroll
        for (int s = 0; s < CT; ++s) {
            float4 v = ((const float4*)(inbase + (size_t)(s0 + s) * PIX))[tid];
            if (BN_IN) {
                const int c = s0 + s;
                const float m   = stats_in[c] * IC_;
                const float q   = stats_in[CIN + c] * IC_;
                const float inv = rsqrtf(q - m * m + 1e-5f);
                v.x = lrelu((v.x - m) * inv);
                v.y = lrelu((v.y - m) * inv);
                v.z = lrelu((v.z - m) * inv);
                v.w = lrelu((v.w - m) * inv);
            }
            // real rows start at +32 (row 0): offset 36 floats -> 16B aligned
            ((float4*)(tile + 4 + s * PST + 32))[tid] = v;
        }
        __syncthreads();
#pragma unroll
        for (int s = 0; s < CT; ++s) {
            const int ci = s0 + s;
            const float* tp = tile + 4 + s * PST + 32;   // (row 0, col 0)
            float r[6][3];
#pragma unroll
            for (int ry = 0; ry < 6; ++ry) {
                const int yy = y0 + ry - 1;              // -1..32, halo rows are 0
#pragma unroll
                for (int cx = 0; cx < 3; ++cx) {
                    float v = tp[yy * 32 + x + cx - 1];
                    if (cx == 0) v = mL ? v : 0.f;
                    if (cx == 2) v = mR ? v : 0.f;
                    r[ry][cx] = v;
                }
            }
#pragma unroll
            for (int c = 0; c < COPB; ++c) {
                const float* wp = w + ((size_t)(co0 + c) * CIN + ci) * 9;
#pragma unroll
                for (int ky = 0; ky < 3; ++ky)
#pragma unroll
                    for (int kx = 0; kx < 3; ++kx) {
                        const float wv = wp[ky * 3 + kx];
#pragma unroll
                        for (int j = 0; j < 4; ++j)
                            acc[c][j] += r[ky + j][kx] * wv;
                    }
            }
        }
    }

    // ---- epilogue: bias, store raw, per-channel stats ----
    if (tid < 2 * COPB) red[tid] = 0.f;
    __syncthreads();
#pragma unroll
    for (int c = 0; c < COPB; ++c) {
        const float b = bias[co0 + c];
        float* ob = out + (((size_t)n * Cout + co0 + c) << 10);
        float s = 0.f, q = 0.f;
#pragma unroll
        for (int j = 0; j < 4; ++j) {
            const float v = acc[c][j] + b;
            ob[(y0 + j) * 32 + x] = v;
            s += v; q += v * v;
        }
#pragma unroll
        for (int off = 32; off > 0; off >>= 1) {
            s += __shfl_down(s, off, 64);
            q += __shfl_down(q, off, 64);
        }
        if ((tid & 63) == 0) {
            atomicAdd(&red[c], s);
            atomicAdd(&red[COPB + c], q);
        }
    }
    __syncthreads();
    if (tid < COPB)
        atomicAdd(&stats_out[co0 + tid], red[tid]);
    else if (tid < 2 * COPB)
        atomicAdd(&stats_out[Cout + co0 + tid - COPB], red[tid]);
}

// ================= fp32 GEMM, 128x128 tile, 8x8 microtile, split-K atomics ===
// C[m][n] += sum_k A[m][k]*B[n][k]. Two heads fused via blockIdx.x.
// If BN_A: A is raw conv output, channel = k>>10, BN+lrelu while staging.
template<bool BN_A>
__global__ __launch_bounds__(256, 2) void gemm128(
    const float* __restrict__ A0, const float* __restrict__ A1,
    const float* __restrict__ B0, const float* __restrict__ B1,
    float* __restrict__ C0, float* __restrict__ C1,
    int K, int Nh, int kchunk, int xph,
    const float* __restrict__ bnstats, int Cin)
{
    __shared__ float As[16][132];
    __shared__ float Bs[16][132];
    const int tid  = threadIdx.x;
    const int head = blockIdx.x / xph;
    const int n0   = (blockIdx.x % xph) * 128;
    const int m0   = blockIdx.y * 128;
    const float* A = head ? A1 : A0;
    const float* B = head ? B1 : B0;
    float*       C = head ? C1 : C0;
    const int k0 = blockIdx.z * kchunk;
    const int k1 = k0 + kchunk;
    const int row = tid >> 2;          // 0..63
    const int kq  = (tid & 3) * 4;     // 0,4,8,12
    const int tx  = tid & 15, ty = tid >> 4;

    float acc[8][8];
#pragma unroll
    for (int i = 0; i < 8; ++i)
#pragma unroll
        for (int j = 0; j < 8; ++j) acc[i][j] = 0.f;

    for (int kb = k0; kb < k1; kb += 16) {
        __syncthreads();
#pragma unroll
        for (int s = 0; s < 2; ++s) {
            const int r = row + s * 64;
            float4 av = *(const float4*)(A + (size_t)(m0 + r) * K + kb + kq);
            if (BN_A) {
                const int c = (kb + kq) >> 10;
                const float m   = bnstats[c] * IC_;
                const float q   = bnstats[Cin + c] * IC_;
                const float inv = rsqrtf(q - m * m + 1e-5f);
                av.x = lrelu((av.x - m) * inv);
                av.y = lrelu((av.y - m) * inv);
                av.z = lrelu((av.z - m) * inv);
                av.w = lrelu((av.w - m) * inv);
            }
            As[kq + 0][r] = av.x; As[kq + 1][r] = av.y;
            As[kq + 2][r] = av.z; As[kq + 3][r] = av.w;
            float4 bv = *(const float4*)(B + (size_t)(n0 + r) * K + kb + kq);
            Bs[kq + 0][r] = bv.x; Bs[kq + 1][r] = bv.y;
            Bs[kq + 2][r] = bv.z; Bs[kq + 3][r] = bv.w;
        }
        __syncthreads();
#pragma unroll
        for (int kk = 0; kk < 16; ++kk) {
            const float4 a0 = *(const float4*)&As[kk][ty * 4];
            const float4 a1 = *(const float4*)&As[kk][64 + ty * 4];
            const float4 b0 = *(const float4*)&Bs[kk][tx * 4];
            const float4 b1 = *(const float4*)&Bs[kk][64 + tx * 4];
            const float ar[8] = {a0.x, a0.y, a0.z, a0.w, a1.x, a1.y, a1.z, a1.w};
            const float br[8] = {b0.x, b0.y, b0.z, b0.w, b1.x, b1.y, b1.z, b1.w};
#pragma unroll
            for (int i = 0; i < 8; ++i)
#pragma unroll
                for (int j = 0; j < 8; ++j)
                    acc[i][j] += ar[i] * br[j];
        }
    }
#pragma unroll
    for (int i = 0; i < 8; ++i) {
        const int m = m0 + ((i >> 2) << 6) + ty * 4 + (i & 3);
        float* crow = C + (size_t)m * Nh + n0;
#pragma unroll
        for (int j = 0; j < 8; ++j) {
            const int nn = ((j >> 2) << 6) + tx * 4 + (j & 3);
            atomicAdd(&crow[nn], acc[i][j]);
        }
    }
}

// ================= bias + leaky relu, in place =================
__global__ __launch_bounds__(256) void bias_lrelu_kernel(
    float* __restrict__ buf, const float* __restrict__ b, int Nn, int total)
{
    const int idx = blockIdx.x * 256 + threadIdx.x;
    if (idx >= total) return;
    buf[idx] = lrelu(buf[idx] + b[idx % Nn]);
}

// ================= block reduce + atomic helper =================
__device__ __forceinline__ void block_reduce_atomic(float t, float* target)
{
#pragma unroll
    for (int off = 32; off > 0; off >>= 1) t += __shfl_down(t, off, 64);
    __shared__ float lt[4];
    const int wave = threadIdx.x >> 6, lane = threadIdx.x & 63;
    if (lane == 0) lt[wave] = t;
    __syncthreads();
    if (threadIdx.x == 0) atomicAdd(target, lt[0] + lt[1] + lt[2] + lt[3]);
}

// ================= product-of-experts group posterior + kl2 =================
__global__ __launch_bounds__(256) void poe_kernel(
    const float* __restrict__ mu1, const float* __restrict__ lv1,
    float* __restrict__ gmu, float* __restrict__ glv, float* __restrict__ kl)
{
    const int l = blockIdx.x * 256 + threadIdx.x;   // 0..1023 (exact)
    float sp = 0.f, sm = 0.f;
    for (int n = 0; n < N_; ++n) {
        const float lv = lv1[(size_t)n * L_ + l];
        const float p  = expf(-lv);
        sp += p;
        sm += mu1[(size_t)n * L_ + l] * p;
    }
    const float gv = 1.f / sp;
    const float gm = sm * gv;
    const float gl = -logf(sp);
    gmu[l] = gm;
    glv[l] = gl;
    const float t = -0.5f * (1.f + gl) + 0.5f * (gm * gm + gv * gv);
    block_reduce_atomic(t, &kl[1]);
}

// ================= reparameterize + kl1 =================
__global__ __launch_bounds__(256) void reparam_kernel(
    const float* __restrict__ mu0, const float* __restrict__ lv0,
    const float* __restrict__ eps_c, const float* __restrict__ eps_s,
    const float* __restrict__ gmu, const float* __restrict__ glv,
    float* __restrict__ zc, float* __restrict__ zs, float* __restrict__ kl)
{
    const int idx = blockIdx.x * 256 + threadIdx.x;   // 0..524287 (exact)
    const int l = idx & (L_ - 1);
    const float m  = mu0[idx];
    const float lv = lv0[idx];
    zc[idx] = eps_c[idx] * expf(0.5f * lv) + m;
    zs[idx] = eps_s[idx] * expf(0.5f * glv[l]) + gmu[l];
    const float e = expf(lv);
    const float t = -0.5f * (1.f + lv) + 0.5f * (m * m + e * e);
    block_reduce_atomic(t, &kl[0]);
}

// ================= final: BN of decoder outputs + output + loss ============
__global__ __launch_bounds__(256) void final_kernel(
    const float* __restrict__ x, const float* __restrict__ oc,
    const float* __restrict__ os, const float* __restrict__ stC,
    const float* __restrict__ stS, const float* __restrict__ kl,
    float* __restrict__ out)
{
    const int idx = blockIdx.x * 256 + threadIdx.x;   // 0..524287 (exact)
    const float mc = stC[0] * IC_, qc = stC[1] * IC_;
    const float ivc = rsqrtf(qc - mc * mc + 1e-5f);
    const float ms = stS[0] * IC_, qs = stS[1] * IC_;
    const float ivs = rsqrtf(qs - ms * ms + 1e-5f);
    const float tc = lrelu((oc[idx] - mc) * ivc);          // output_c (bn+lrelu)
    const float ts = fmaxf((os[idx] - ms) * ivs, 0.f);     // relu(lrelu(bn)) = relu(bn)
    const float o = tc * ts;
    const float d = expf(x[idx]) - expf(o);
    out[idx]            = -kl[0] + kl[1] + d * d;
    out[N_ * PIX + idx] = o;
}

// ================= host launch =================
extern "C" void kernel_launch(void* const* d_in, const int* in_sizes, int n_in,
                              void* d_out, int out_size, void* d_ws, size_t ws_size,
                              hipStream_t stream)
{
    const float* x        = (const float*)d_in[0];
    const float* eps_c    = (const float*)d_in[1];
    const float* eps_s    = (const float*)d_in[2];
    const float* enc_cw1  = (const float*)d_in[3];
    const float* enc_cb1  = (const float*)d_in[4];
    const float* enc_cw2  = (const float*)d_in[5];
    const float* enc_cb2  = (const float*)d_in[6];
    const float* enc_cw3  = (const float*)d_in[7];
    const float* enc_cb3  = (const float*)d_in[8];
    const float* enc_muW1 = (const float*)d_in[9];
    const float* enc_muB1 = (const float*)d_in[10];
    const float* enc_muW2 = (const float*)d_in[11];
    const float* enc_muB2 = (const float*)d_in[12];
    const float* enc_vaW1 = (const float*)d_in[13];
    const float* enc_vaB1 = (const float*)d_in[14];
    const float* enc_vaW2 = (const float*)d_in[15];
    const float* enc_vaB2 = (const float*)d_in[16];
    const float* dec_cw1  = (const float*)d_in[17];
    const float* dec_cb1  = (const float*)d_in[18];
    const float* dec_cw2  = (const float*)d_in[19];
    const float* dec_cb2  = (const float*)d_in[20];
    const float* dec_cw3  = (const float*)d_in[21];
    const float* dec_cb3  = (const float*)d_in[22];
    float* out = (float*)d_out;

    // ---- workspace layout (floats) ----
    float* ws   = (float*)d_ws;
    float* bufA = ws;                             // N*64*PIX
    float* bufB = bufA + (size_t)N_ * 64 * PIX;   // N*32*PIX
    float* h1   = bufB + (size_t)N_ * 32 * PIX;   // N*H
    float* h2   = h1 + N_ * H_;
    float* mu0  = h2 + N_ * H_;                   // N*L each below
    float* lv0  = mu0 + N_ * L_;
    float* mu1  = lv0 + N_ * L_;
    float* lv1  = mu1 + N_ * L_;
    float* zc   = lv1 + N_ * L_;
    float* zs   = zc + N_ * L_;
    float* oc   = zs + N_ * L_;
    float* os   = oc + N_ * L_;
    float* gmu  = os + N_ * L_;                   // L
    float* glv  = gmu + L_;                       // L
    float* stats = glv + L_;                      // 12 slots x 128
    float* kl   = stats + 12 * 128;               // 2

    auto st = [&](int s) { return stats + 128 * s; };

    hipMemsetAsync(stats, 0, 12 * 128 * sizeof(float), stream);
    hipMemsetAsync(kl, 0, 2 * sizeof(float), stream);

    // ================== encoders ==================
    for (int i = 0; i < 2; ++i) {
        const float* cw1 = enc_cw1 + (size_t)i * 32 * 9;
        const float* cb1 = enc_cb1 + (size_t)i * 32;
        const float* cw2 = enc_cw2 + (size_t)i * 64 * 32 * 9;
        const float* cb2 = enc_cb2 + (size_t)i * 64;
        const float* cw3 = enc_cw3 + (size_t)i * 32 * 64 * 9;
        const float* cb3 = enc_cb3 + (size_t)i * 32;

        conv3x3<1, 16, false><<<N_ * 2, 256, 0, stream>>>(
            x, cw1, cb1, bufB, nullptr, st(i * 3 + 0), 32);
        conv3x3<32, 16, true><<<N_ * 4, 256, 0, stream>>>(
            bufB, cw2, cb2, bufA, st(i * 3 + 0), st(i * 3 + 1), 64);
        conv3x3<64, 16, true><<<N_ * 2, 256, 0, stream>>>(
            bufA, cw3, cb3, bufB, st(i * 3 + 1), st(i * 3 + 2), 32);
        // bufB = raw conv3 out; BN+lrelu fused into GEMM A staging

        const float* W1m = enc_muW1 + (size_t)i * H_ * F_;
        const float* B1m = enc_muB1 + (size_t)i * H_;
        const float* W2m = enc_muW2 + (size_t)i * L_ * H_;
        const float* B2m = enc_muB2 + (size_t)i * L_;
        const float* W1v = enc_vaW1 + (size_t)i * H_ * F_;
        const float* B1v = enc_vaB1 + (size_t)i * H_;
        const float* W2v = enc_vaW2 + (size_t)i * L_ * H_;
        const float* B2v = enc_vaB2 + (size_t)i * L_;
        float* mu_i = (i == 0) ? mu0 : mu1;
        float* lv_i = (i == 0) ? lv0 : lv1;

        hipMemsetAsync(h1, 0, (size_t)N_ * H_ * sizeof(float), stream);
        hipMemsetAsync(h2, 0, (size_t)N_ * H_ * sizeof(float), stream);
        // fused mu+va heads: grid.x = 2 heads * (512/128) = 8
        gemm128<true><<<dim3(8, 4, 16), 256, 0, stream>>>(
            bufB, bufB, W1m, W1v, h1, h2, F_, H_, 2048, 4, st(i * 3 + 2), 32);
        bias_lrelu_kernel<<<(N_ * H_) / 256, 256, 0, stream>>>(h1, B1m, H_, N_ * H_);
        bias_lrelu_kernel<<<(N_ * H_) / 256, 256, 0, stream>>>(h2, B1v, H_, N_ * H_);

        hipMemsetAsync(mu_i, 0, (size_t)N_ * L_ * sizeof(float), stream);
        hipMemsetAsync(lv_i, 0, (size_t)N_ * L_ * sizeof(float), stream);
        gemm128<false><<<dim3(16, 4, 4), 256, 0, stream>>>(
            h1, h2, W2m, W2v, mu_i, lv_i, H_, L_, 128, 8, nullptr, 0);
        bias_lrelu_kernel<<<(N_ * L_) / 256, 256, 0, stream>>>(mu_i, B2m, L_, N_ * L_);
        bias_lrelu_kernel<<<(N_ * L_) / 256, 256, 0, stream>>>(lv_i, B2v, L_, N_ * L_);
    }

    // ================== PoE + reparam + KL ==================
    poe_kernel<<<L_ / 256, 256, 0, stream>>>(mu1, lv1, gmu, glv, kl);
    reparam_kernel<<<(N_ * L_) / 256, 256, 0, stream>>>(
        mu0, lv0, eps_c, eps_s, gmu, glv, zc, zs, kl);

    // ================== decoders ==================
    for (int i = 0; i < 2; ++i) {
        const float* cw1 = dec_cw1 + (size_t)i * 32 * 9;
        const float* cb1 = dec_cb1 + (size_t)i * 32;
        const float* cw2 = dec_cw2 + (size_t)i * 64 * 32 * 9;
        const float* cb2 = dec_cb2 + (size_t)i * 64;
        const float* cw3 = dec_cw3 + (size_t)i * 64 * 9;
        const float* cb3 = dec_cb3 + (size_t)i * 1;
        const float* zi = (i == 0) ? zc : zs;
        float* oi = (i == 0) ? oc : os;

        conv3x3<1, 16, false><<<N_ * 2, 256, 0, stream>>>(
            zi, cw1, cb1, bufB, nullptr, st(6 + i * 3 + 0), 32);
        conv3x3<32, 16, true><<<N_ * 4, 256, 0, stream>>>(
            bufB, cw2, cb2, bufA, st(6 + i * 3 + 0), st(6 + i * 3 + 1), 64);
        conv3x3<64, 1, true><<<N_, 256, 0, stream>>>(
            bufA, cw3, cb3, oi, st(6 + i * 3 + 1), st(6 + i * 3 + 2), 1);
    }

    // ================== output + loss (BN of oc/os fused) ==================
    final_kernel<<<(N_ * PIX) / 256, 256, 0, stream>>>(
        x, oc, os, st(8), st(11), kl, out);
}

// Round 4
// 4430.716 us; speedup vs baseline: 1.6538x; 1.6538x over previous
//
#include <hip/hip_runtime.h>

// ---------------- problem constants ----------------
constexpr int N_   = 512;
constexpr int PIX  = 1024;    // 32*32
constexpr int L_   = 1024;
constexpr int F_   = 32768;   // 32*32*32
constexpr int H_   = 512;
constexpr float IC_ = 1.0f / (float)(512 * 1024);   // 1/(N*PIX), BN count

__device__ __forceinline__ float lrelu(float t) { return t >= 0.f ? t : 0.01f * t; }

// ================= conv 3x3 SAME, NCHW — fused input-BN + stats epilogue ======
// Round-2 structure (VGPR=84 proven), CT=4 (16.5 KB LDS -> ~6 blocks/CU vs 2).
// Block: 256 threads, one n, COPB output channels. Thread owns a 4-px vertical
// strip (rows y0..y0+3, col x): wave covers 32 cols -> 2-way LDS reads (free).
// If BN_IN: BN+lrelu (from raw sums in stats_in) applied while staging.
// Epilogue: writes raw conv+bias, block-reduces per-channel sum/sumsq into
// stats_out[{c, Cout+c}].
template<int CIN, int COPB, bool BN_IN>
__global__ __launch_bounds__(256) void conv3x3(
    const float* __restrict__ in, const float* __restrict__ w,
    const float* __restrict__ bias, float* __restrict__ out,
    const float* __restrict__ stats_in, float* __restrict__ stats_out,
    int Cout)
{
    constexpr int CT = (CIN < 4) ? CIN : 4;
    __shared__ float tile[CT * PIX];
    __shared__ float red[2 * COPB];
    const int groups = Cout / COPB;
    const int n   = blockIdx.x / groups;
    const int co0 = (blockIdx.x % groups) * COPB;
    const int tid = threadIdx.x;
    const int x   = tid & 31;
    const int y0  = (tid >> 5) * 4;

    float acc[COPB][4];
#pragma unroll
    for (int c = 0; c < COPB; ++c)
#pragma unroll
        for (int j = 0; j < 4; ++j) acc[c][j] = 0.f;

    const float* inbase = in + (size_t)n * CIN * PIX;

#pragma unroll 1
    for (int s0 = 0; s0 < CIN; s0 += CT) {
        __syncthreads();
#pragma unroll
        for (int s = 0; s < CT; ++s) {
            float4 v = ((const float4*)(inbase + (size_t)(s0 + s) * PIX))[tid];
            if (BN_IN) {
                const int c = s0 + s;
                const float m   = stats_in[c] * IC_;
                const float q   = stats_in[CIN + c] * IC_;
                const float inv = rsqrtf(q - m * m + 1e-5f);
                v.x = lrelu((v.x - m) * inv);
                v.y = lrelu((v.y - m) * inv);
                v.z = lrelu((v.z - m) * inv);
                v.w = lrelu((v.w - m) * inv);
            }
            ((float4*)tile)[s * 256 + tid] = v;
        }
        __syncthreads();
#pragma unroll 2
        for (int s = 0; s < CT; ++s) {
            const int ci = s0 + s;
            const float* tp = tile + s * PIX;
            // window: rows y0-1..y0+4, cols x-1..x+1
            float r[6][3];
#pragma unroll
            for (int ry = 0; ry < 6; ++ry) {
                const int yy = y0 + ry - 1;
                const bool yok = (unsigned)yy < 32u;
#pragma unroll
                for (int cx = 0; cx < 3; ++cx) {
                    const int xx = x + cx - 1;
                    const bool ok = yok && ((unsigned)xx < 32u);
                    r[ry][cx] = ok ? tp[yy * 32 + xx] : 0.f;
                }
            }
#pragma unroll
            for (int c = 0; c < COPB; ++c) {
                const float* wp = w + ((size_t)(co0 + c) * CIN + ci) * 9;
#pragma unroll
                for (int ky = 0; ky < 3; ++ky)
#pragma unroll
                    for (int kx = 0; kx < 3; ++kx) {
                        const float wv = wp[ky * 3 + kx];
#pragma unroll
                        for (int j = 0; j < 4; ++j)
                            acc[c][j] += r[ky + j][kx] * wv;
                    }
            }
        }
    }

    // ---- epilogue: bias, store raw, per-channel stats ----
    if (tid < 2 * COPB) red[tid] = 0.f;
    __syncthreads();
#pragma unroll
    for (int c = 0; c < COPB; ++c) {
        const float b = bias[co0 + c];
        float* ob = out + (((size_t)n * Cout + co0 + c) << 10);
        float s = 0.f, q = 0.f;
#pragma unroll
        for (int j = 0; j < 4; ++j) {
            const float v = acc[c][j] + b;
            ob[(y0 + j) * 32 + x] = v;
            s += v; q += v * v;
        }
#pragma unroll
        for (int off = 32; off > 0; off >>= 1) {
            s += __shfl_down(s, off, 64);
            q += __shfl_down(q, off, 64);
        }
        if ((tid & 63) == 0) {
            atomicAdd(&red[c], s);
            atomicAdd(&red[COPB + c], q);
        }
    }
    __syncthreads();
    if (tid < COPB)
        atomicAdd(&stats_out[co0 + tid], red[tid]);
    else if (tid < 2 * COPB)
        atomicAdd(&stats_out[Cout + co0 + tid - COPB], red[tid]);
}

// ================= fp32 GEMM, 128x128 tile, 8x8 microtile, split-K atomics ===
// C[m][n] += sum_k A[m][k]*B[n][k]. Two heads fused via blockIdx.x.
// If BN_A: A is raw conv output, channel = k>>10, BN+lrelu while staging.
template<bool BN_A>
__global__ __launch_bounds__(256, 2) void gemm128(
    const float* __restrict__ A0, const float* __restrict__ A1,
    const float* __restrict__ B0, const float* __restrict__ B1,
    float* __restrict__ C0, float* __restrict__ C1,
    int K, int Nh, int kchunk, int xph,
    const float* __restrict__ bnstats, int Cin)
{
    __shared__ float As[16][132];
    __shared__ float Bs[16][132];
    const int tid  = threadIdx.x;
    const int head = blockIdx.x / xph;
    const int n0   = (blockIdx.x % xph) * 128;
    const int m0   = blockIdx.y * 128;
    const float* A = head ? A1 : A0;
    const float* B = head ? B1 : B0;
    float*       C = head ? C1 : C0;
    const int k0 = blockIdx.z * kchunk;
    const int k1 = k0 + kchunk;
    const int row = tid >> 2;          // 0..63
    const int kq  = (tid & 3) * 4;     // 0,4,8,12
    const int tx  = tid & 15, ty = tid >> 4;

    float acc[8][8];
#pragma unroll
    for (int i = 0; i < 8; ++i)
#pragma unroll
        for (int j = 0; j < 8; ++j) acc[i][j] = 0.f;

    for (int kb = k0; kb < k1; kb += 16) {
        __syncthreads();
#pragma unroll
        for (int s = 0; s < 2; ++s) {
            const int r = row + s * 64;
            float4 av = *(const float4*)(A + (size_t)(m0 + r) * K + kb + kq);
            if (BN_A) {
                const int c = (kb + kq) >> 10;
                const float m   = bnstats[c] * IC_;
                const float q   = bnstats[Cin + c] * IC_;
                const float inv = rsqrtf(q - m * m + 1e-5f);
                av.x = lrelu((av.x - m) * inv);
                av.y = lrelu((av.y - m) * inv);
                av.z = lrelu((av.z - m) * inv);
                av.w = lrelu((av.w - m) * inv);
            }
            As[kq + 0][r] = av.x; As[kq + 1][r] = av.y;
            As[kq + 2][r] = av.z; As[kq + 3][r] = av.w;
            float4 bv = *(const float4*)(B + (size_t)(n0 + r) * K + kb + kq);
            Bs[kq + 0][r] = bv.x; Bs[kq + 1][r] = bv.y;
            Bs[kq + 2][r] = bv.z; Bs[kq + 3][r] = bv.w;
        }
        __syncthreads();
#pragma unroll
        for (int kk = 0; kk < 16; ++kk) {
            const float4 a0 = *(const float4*)&As[kk][ty * 4];
            const float4 a1 = *(const float4*)&As[kk][64 + ty * 4];
            const float4 b0 = *(const float4*)&Bs[kk][tx * 4];
            const float4 b1 = *(const float4*)&Bs[kk][64 + tx * 4];
            const float ar[8] = {a0.x, a0.y, a0.z, a0.w, a1.x, a1.y, a1.z, a1.w};
            const float br[8] = {b0.x, b0.y, b0.z, b0.w, b1.x, b1.y, b1.z, b1.w};
#pragma unroll
            for (int i = 0; i < 8; ++i)
#pragma unroll
                for (int j = 0; j < 8; ++j)
                    acc[i][j] += ar[i] * br[j];
        }
    }
#pragma unroll
    for (int i = 0; i < 8; ++i) {
        const int m = m0 + ((i >> 2) << 6) + ty * 4 + (i & 3);
        float* crow = C + (size_t)m * Nh + n0;
#pragma unroll
        for (int j = 0; j < 8; ++j) {
            const int nn = ((j >> 2) << 6) + tx * 4 + (j & 3);
            atomicAdd(&crow[nn], acc[i][j]);
        }
    }
}

// ================= bias + leaky relu, in place =================
__global__ __launch_bounds__(256) void bias_lrelu_kernel(
    float* __restrict__ buf, const float* __restrict__ b, int Nn, int total)
{
    const int idx = blockIdx.x * 256 + threadIdx.x;
    if (idx >= total) return;
    buf[idx] = lrelu(buf[idx] + b[idx % Nn]);
}

// ================= block reduce + atomic helper =================
__device__ __forceinline__ void block_reduce_atomic(float t, float* target)
{
#pragma unroll
    for (int off = 32; off > 0; off >>= 1) t += __shfl_down(t, off, 64);
    __shared__ float lt[4];
    const int wave = threadIdx.x >> 6, lane = threadIdx.x & 63;
    if (lane == 0) lt[wave] = t;
    __syncthreads();
    if (threadIdx.x == 0) atomicAdd(target, lt[0] + lt[1] + lt[2] + lt[3]);
}

// ================= product-of-experts group posterior + kl2 =================
__global__ __launch_bounds__(256) void poe_kernel(
    const float* __restrict__ mu1, const float* __restrict__ lv1,
    float* __restrict__ gmu, float* __restrict__ glv, float* __restrict__ kl)
{
    const int l = blockIdx.x * 256 + threadIdx.x;   // 0..1023 (exact)
    float sp = 0.f, sm = 0.f;
    for (int n = 0; n < N_; ++n) {
        const float lv = lv1[(size_t)n * L_ + l];
        const float p  = expf(-lv);
        sp += p;
        sm += mu1[(size_t)n * L_ + l] * p;
    }
    const float gv = 1.f / sp;
    const float gm = sm * gv;
    const float gl = -logf(sp);
    gmu[l] = gm;
    glv[l] = gl;
    const float t = -0.5f * (1.f + gl) + 0.5f * (gm * gm + gv * gv);
    block_reduce_atomic(t, &kl[1]);
}

// ================= reparameterize + kl1 =================
__global__ __launch_bounds__(256) void reparam_kernel(
    const float* __restrict__ mu0, const float* __restrict__ lv0,
    const float* __restrict__ eps_c, const float* __restrict__ eps_s,
    const float* __restrict__ gmu, const float* __restrict__ glv,
    float* __restrict__ zc, float* __restrict__ zs, float* __restrict__ kl)
{
    const int idx = blockIdx.x * 256 + threadIdx.x;   // 0..524287 (exact)
    const int l = idx & (L_ - 1);
    const float m  = mu0[idx];
    const float lv = lv0[idx];
    zc[idx] = eps_c[idx] * expf(0.5f * lv) + m;
    zs[idx] = eps_s[idx] * expf(0.5f * glv[l]) + gmu[l];
    const float e = expf(lv);
    const float t = -0.5f * (1.f + lv) + 0.5f * (m * m + e * e);
    block_reduce_atomic(t, &kl[0]);
}

// ================= final: BN of decoder outputs + output + loss ============
__global__ __launch_bounds__(256) void final_kernel(
    const float* __restrict__ x, const float* __restrict__ oc,
    const float* __restrict__ os, const float* __restrict__ stC,
    const float* __restrict__ stS, const float* __restrict__ kl,
    float* __restrict__ out)
{
    const int idx = blockIdx.x * 256 + threadIdx.x;   // 0..524287 (exact)
    const float mc = stC[0] * IC_, qc = stC[1] * IC_;
    const float ivc = rsqrtf(qc - mc * mc + 1e-5f);
    const float ms = stS[0] * IC_, qs = stS[1] * IC_;
    const float ivs = rsqrtf(qs - ms * ms + 1e-5f);
    const float tc = lrelu((oc[idx] - mc) * ivc);          // output_c (bn+lrelu)
    const float ts = fmaxf((os[idx] - ms) * ivs, 0.f);     // relu(lrelu(bn)) = relu(bn)
    const float o = tc * ts;
    const float d = expf(x[idx]) - expf(o);
    out[idx]            = -kl[0] + kl[1] + d * d;
    out[N_ * PIX + idx] = o;
}

// ================= host launch =================
extern "C" void kernel_launch(void* const* d_in, const int* in_sizes, int n_in,
                              void* d_out, int out_size, void* d_ws, size_t ws_size,
                              hipStream_t stream)
{
    const float* x        = (const float*)d_in[0];
    const float* eps_c    = (const float*)d_in[1];
    const float* eps_s    = (const float*)d_in[2];
    const float* enc_cw1  = (const float*)d_in[3];
    const float* enc_cb1  = (const float*)d_in[4];
    const float* enc_cw2  = (const float*)d_in[5];
    const float* enc_cb2  = (const float*)d_in[6];
    const float* enc_cw3  = (const float*)d_in[7];
    const float* enc_cb3  = (const float*)d_in[8];
    const float* enc_muW1 = (const float*)d_in[9];
    const float* enc_muB1 = (const float*)d_in[10];
    const float* enc_muW2 = (const float*)d_in[11];
    const float* enc_muB2 = (const float*)d_in[12];
    const float* enc_vaW1 = (const float*)d_in[13];
    const float* enc_vaB1 = (const float*)d_in[14];
    const float* enc_vaW2 = (const float*)d_in[15];
    const float* enc_vaB2 = (const float*)d_in[16];
    const float* dec_cw1  = (const float*)d_in[17];
    const float* dec_cb1  = (const float*)d_in[18];
    const float* dec_cw2  = (const float*)d_in[19];
    const float* dec_cb2  = (const float*)d_in[20];
    const float* dec_cw3  = (const float*)d_in[21];
    const float* dec_cb3  = (const float*)d_in[22];
    float* out = (float*)d_out;

    // ---- workspace layout (floats) ----
    float* ws   = (float*)d_ws;
    float* bufA = ws;                             // N*64*PIX
    float* bufB = bufA + (size_t)N_ * 64 * PIX;   // N*32*PIX
    float* h1   = bufB + (size_t)N_ * 32 * PIX;   // N*H
    float* h2   = h1 + N_ * H_;
    float* mu0  = h2 + N_ * H_;                   // N*L each below
    float* lv0  = mu0 + N_ * L_;
    float* mu1  = lv0 + N_ * L_;
    float* lv1  = mu1 + N_ * L_;
    float* zc   = lv1 + N_ * L_;
    float* zs   = zc + N_ * L_;
    float* oc   = zs + N_ * L_;
    float* os   = oc + N_ * L_;
    float* gmu  = os + N_ * L_;                   // L
    float* glv  = gmu + L_;                       // L
    float* stats = glv + L_;                      // 12 slots x 128
    float* kl   = stats + 12 * 128;               // 2

    auto st = [&](int s) { return stats + 128 * s; };

    hipMemsetAsync(stats, 0, 12 * 128 * sizeof(float), stream);
    hipMemsetAsync(kl, 0, 2 * sizeof(float), stream);

    // ================== encoders ==================
    for (int i = 0; i < 2; ++i) {
        const float* cw1 = enc_cw1 + (size_t)i * 32 * 9;
        const float* cb1 = enc_cb1 + (size_t)i * 32;
        const float* cw2 = enc_cw2 + (size_t)i * 64 * 32 * 9;
        const float* cb2 = enc_cb2 + (size_t)i * 64;
        const float* cw3 = enc_cw3 + (size_t)i * 32 * 64 * 9;
        const float* cb3 = enc_cb3 + (size_t)i * 32;

        conv3x3<1, 16, false><<<N_ * 2, 256, 0, stream>>>(
            x, cw1, cb1, bufB, nullptr, st(i * 3 + 0), 32);
        conv3x3<32, 16, true><<<N_ * 4, 256, 0, stream>>>(
            bufB, cw2, cb2, bufA, st(i * 3 + 0), st(i * 3 + 1), 64);
        conv3x3<64, 16, true><<<N_ * 2, 256, 0, stream>>>(
            bufA, cw3, cb3, bufB, st(i * 3 + 1), st(i * 3 + 2), 32);
        // bufB = raw conv3 out; BN+lrelu fused into GEMM A staging

        const float* W1m = enc_muW1 + (size_t)i * H_ * F_;
        const float* B1m = enc_muB1 + (size_t)i * H_;
        const float* W2m = enc_muW2 + (size_t)i * L_ * H_;
        const float* B2m = enc_muB2 + (size_t)i * L_;
        const float* W1v = enc_vaW1 + (size_t)i * H_ * F_;
        const float* B1v = enc_vaB1 + (size_t)i * H_;
        const float* W2v = enc_vaW2 + (size_t)i * L_ * H_;
        const float* B2v = enc_vaB2 + (size_t)i * L_;
        float* mu_i = (i == 0) ? mu0 : mu1;
        float* lv_i = (i == 0) ? lv0 : lv1;

        hipMemsetAsync(h1, 0, (size_t)N_ * H_ * sizeof(float), stream);
        hipMemsetAsync(h2, 0, (size_t)N_ * H_ * sizeof(float), stream);
        // fused mu+va heads: grid.x = 2 heads * (512/128) = 8
        gemm128<true><<<dim3(8, 4, 16), 256, 0, stream>>>(
            bufB, bufB, W1m, W1v, h1, h2, F_, H_, 2048, 4, st(i * 3 + 2), 32);
        bias_lrelu_kernel<<<(N_ * H_) / 256, 256, 0, stream>>>(h1, B1m, H_, N_ * H_);
        bias_lrelu_kernel<<<(N_ * H_) / 256, 256, 0, stream>>>(h2, B1v, H_, N_ * H_);

        hipMemsetAsync(mu_i, 0, (size_t)N_ * L_ * sizeof(float), stream);
        hipMemsetAsync(lv_i, 0, (size_t)N_ * L_ * sizeof(float), stream);
        gemm128<false><<<dim3(16, 4, 4), 256, 0, stream>>>(
            h1, h2, W2m, W2v, mu_i, lv_i, H_, L_, 128, 8, nullptr, 0);
        bias_lrelu_kernel<<<(N_ * L_) / 256, 256, 0, stream>>>(mu_i, B2m, L_, N_ * L_);
        bias_lrelu_kernel<<<(N_ * L_) / 256, 256, 0, stream>>>(lv_i, B2v, L_, N_ * L_);
    }

    // ================== PoE + reparam + KL ==================
    poe_kernel<<<L_ / 256, 256, 0, stream>>>(mu1, lv1, gmu, glv, kl);
    reparam_kernel<<<(N_ * L_) / 256, 256, 0, stream>>>(
        mu0, lv0, eps_c, eps_s, gmu, glv, zc, zs, kl);

    // ================== decoders ==================
    for (int i = 0; i < 2; ++i) {
        const float* cw1 = dec_cw1 + (size_t)i * 32 * 9;
        const float* cb1 = dec_cb1 + (size_t)i * 32;
        const float* cw2 = dec_cw2 + (size_t)i * 64 * 32 * 9;
        const float* cb2 = dec_cb2 + (size_t)i * 64;
        const float* cw3 = dec_cw3 + (size_t)i * 64 * 9;
        const float* cb3 = dec_cb3 + (size_t)i * 1;
        const float* zi = (i == 0) ? zc : zs;
        float* oi = (i == 0) ? oc : os;

        conv3x3<1, 16, false><<<N_ * 2, 256, 0, stream>>>(
            zi, cw1, cb1, bufB, nullptr, st(6 + i * 3 + 0), 32);
        conv3x3<32, 16, true><<<N_ * 4, 256, 0, stream>>>(
            bufB, cw2, cb2, bufA, st(6 + i * 3 + 0), st(6 + i * 3 + 1), 64);
        conv3x3<64, 1, true><<<N_, 256, 0, stream>>>(
            bufA, cw3, cb3, oi, st(6 + i * 3 + 1), st(6 + i * 3 + 2), 1);
    }

    // ================== output + loss (BN of oc/os fused) ==================
    final_kernel<<<(N_ * PIX) / 256, 256, 0, stream>>>(
        x, oc, os, st(8), st(11), kl, out);
}